// Round 1
// baseline (223.861 us; speedup 1.0000x reference)
//
#include <hip/hip_runtime.h>
#include <hip/hip_bf16.h>

typedef unsigned short u16;
typedef unsigned int u32;
typedef __attribute__((ext_vector_type(4))) float f32x4;
typedef __attribute__((ext_vector_type(8))) short bf16x8;

__device__ inline u16 f2bf(float f) {
    union { float f; u32 u; } v; v.f = f;
    u32 r = v.u + 0x7fff + ((v.u >> 16) & 1);
    return (u16)(r >> 16);
}

__device__ inline f32x4 mfma16(bf16x8 a, bf16x8 b, f32x4 c) {
    return __builtin_amdgcn_mfma_f32_16x16x32_bf16(a, b, c, 0, 0, 0);
}

__device__ inline void gload_lds16(const void* g, const void* l) {
    __builtin_amdgcn_global_load_lds(
        (const __attribute__((address_space(1))) void*)g,
        (__attribute__((address_space(3))) void*)l, 16, 0, 0);
}

// ---------------- fp32 -> bf16 conversion, 8 elems/thread ----------------
__global__ void cvt_kernel(const float* __restrict__ in, u16* __restrict__ out, int n8) {
    int i = blockIdx.x * 256 + threadIdx.x;
    if (i >= n8) return;
    const float4* p = (const float4*)in;
    float4 a = p[2 * i], b = p[2 * i + 1];
    bf16x8 v;
    v[0] = (short)f2bf(a.x); v[1] = (short)f2bf(a.y);
    v[2] = (short)f2bf(a.z); v[3] = (short)f2bf(a.w);
    v[4] = (short)f2bf(b.x); v[5] = (short)f2bf(b.y);
    v[6] = (short)f2bf(b.z); v[7] = (short)f2bf(b.w);
    ((bf16x8*)out)[i] = v;
}

// ---------------- GEMM  C[M,N] = A[M,K] * B[N,K]^T  (bf16 in, f32 acc) ---
// 128x128 tile, 4 waves (2x2 of 64x64), BK=32, 2-phase gload_lds dbuf.
// EPI 0: scatter into q/k/v [B*H][N][64] bf16 (+bias, q*0.125)
// EPI 1: fp32 out [M][N] + bias
template <int EPI>
__global__ __launch_bounds__(256) void gemm_bt(
    const u16* __restrict__ A, const u16* __restrict__ B,
    int M, int N, int K,
    u16* __restrict__ qw, u16* __restrict__ kw, u16* __restrict__ vw,
    const float* __restrict__ qb, const float* __restrict__ vb,
    float* __restrict__ outp, const float* __restrict__ bproj)
{
    __shared__ __align__(16) u16 lA[2][128 * 32];
    __shared__ __align__(16) u16 lB[2][128 * 32];
    const int tid = threadIdx.x;
    const int lane = tid & 63;
    const int wv = tid >> 6;
    const int nbn = N >> 7;
    const int bm = blockIdx.x / nbn, bn = blockIdx.x % nbn;
    const int row0 = bm << 7, col0 = bn << 7;

    const int c0 = tid, c1 = tid + 256;                 // 16B chunk ids
    const int ldsOff0 = (wv * 64) * 8;                  // ushort offset, wave-uniform
    const int ldsOff1 = (256 + wv * 64) * 8;

    f32x4 acc[4][4];
#pragma unroll
    for (int i = 0; i < 4; i++)
#pragma unroll
        for (int j = 0; j < 4; j++) acc[i][j] = (f32x4){0.f, 0.f, 0.f, 0.f};

    const int nT = K >> 5;

    auto stage = [&](int buf, int t) {
        const int k0 = t << 5;
        gload_lds16(&A[(size_t)(row0 + (c0 >> 2)) * K + k0 + (c0 & 3) * 8], &lA[buf][ldsOff0]);
        gload_lds16(&A[(size_t)(row0 + (c1 >> 2)) * K + k0 + (c1 & 3) * 8], &lA[buf][ldsOff1]);
        gload_lds16(&B[(size_t)(col0 + (c0 >> 2)) * K + k0 + (c0 & 3) * 8], &lB[buf][ldsOff0]);
        gload_lds16(&B[(size_t)(col0 + (c1 >> 2)) * K + k0 + (c1 & 3) * 8], &lB[buf][ldsOff1]);
    };

    const int wr = (wv >> 1) << 6;   // wave row offset 0/64
    const int wc = (wv & 1) << 6;    // wave col offset 0/64

    stage(0, 0);
    __syncthreads();
    for (int t = 0; t < nT; ++t) {
        if (t + 1 < nT) stage((t + 1) & 1, t + 1);
        const int buf = t & 1;
        const u16* As = &lA[buf][(wr + (lane & 15)) * 32 + ((lane >> 4) * 8)];
        const u16* Bs = &lB[buf][(wc + (lane & 15)) * 32 + ((lane >> 4) * 8)];
        bf16x8 af[4], bfr[4];
#pragma unroll
        for (int i = 0; i < 4; i++) af[i] = *(const bf16x8*)(As + i * 16 * 32);
#pragma unroll
        for (int i = 0; i < 4; i++) bfr[i] = *(const bf16x8*)(Bs + i * 16 * 32);
#pragma unroll
        for (int i = 0; i < 4; i++)
#pragma unroll
            for (int j = 0; j < 4; j++)
                acc[i][j] = mfma16(af[i], bfr[j], acc[i][j]);
        __syncthreads();
    }

    if (EPI == 0) {
        // scatter into q/k/v  [b*12+h][n][d], q scaled by 0.125
#pragma unroll
        for (int nj = 0; nj < 4; ++nj) {
            const int col = col0 + wc + nj * 16 + (lane & 15);
            const int part = col / 768;
            const int rem = col - part * 768;
            const int h = rem >> 6, d = rem & 63;
            const float bias = (part == 0) ? qb[rem] : ((part == 2) ? vb[rem] : 0.f);
            const float sc = (part == 0) ? 0.125f : 1.f;
            u16* dst = (part == 0) ? qw : ((part == 1) ? kw : vw);
#pragma unroll
            for (int mi = 0; mi < 4; ++mi) {
#pragma unroll
                for (int j = 0; j < 4; ++j) {
                    const int row = row0 + wr + mi * 16 + ((lane >> 4) << 2) + j;
                    const int b = row >> 10, n = row & 1023;
                    dst[(size_t)(((b * 12 + h) << 10) + n) * 64 + d] =
                        f2bf((acc[mi][nj][j] + bias) * sc);
                }
            }
        }
    } else {
#pragma unroll
        for (int nj = 0; nj < 4; ++nj) {
            const int col = col0 + wc + nj * 16 + (lane & 15);
            const float bias = bproj[col];
#pragma unroll
            for (int mi = 0; mi < 4; ++mi) {
#pragma unroll
                for (int j = 0; j < 4; ++j) {
                    const int row = row0 + wr + mi * 16 + ((lane >> 4) << 2) + j;
                    outp[(size_t)row * N + col] = acc[mi][nj][j] + bias;
                }
            }
        }
    }
}

// ---------------- flash attention: 1 block = (b,h) x 64 q-rows ----------
// 4 waves x 16 q-rows; KB=32 keys/iter; scale pre-folded into q.
__global__ __launch_bounds__(256) void attn_fwd(
    const u16* __restrict__ Q, const u16* __restrict__ K,
    const u16* __restrict__ V, u16* __restrict__ O)
{
    __shared__ __align__(16) u16 Vt[64 * 40];       // V^T tile, padded stride 40
    __shared__ __align__(16) u16 Pb[4][16 * 40];    // per-wave P tile, stride 40
    const int tid = threadIdx.x, lane = tid & 63, wv = tid >> 6;
    const int bh = blockIdx.x % 96;                 // 96%8==0 -> same bh stays on one XCD
    const int qb = blockIdx.x / 96;
    const u16* Qp = Q + ((size_t)bh << 16);
    const u16* Kp = K + ((size_t)bh << 16);
    const u16* Vp = V + ((size_t)bh << 16);
    const int q0 = (qb << 6) + (wv << 4);

    bf16x8 aq[2];
#pragma unroll
    for (int ks = 0; ks < 2; ++ks)
        aq[ks] = *(const bf16x8*)&Qp[(q0 + (lane & 15)) * 64 + (lane >> 4) * 8 + ks * 32];

    f32x4 o[4]; float m[4], l[4];
#pragma unroll
    for (int i = 0; i < 4; i++) { o[i] = (f32x4){0.f,0.f,0.f,0.f}; m[i] = -1e30f; l[i] = 0.f; }

    u32* Vt32 = (u32*)Vt;
    u16* Pw = &Pb[wv][0];

    for (int kt = 0; kt < 32; ++kt) {
        const int kv0 = kt << 5;
        // stage V^T (threads 0..127): pack key-pairs into u32, write columns
        if (tid < 128) {
            const int kp = tid >> 3, d0 = (tid & 7) << 3;
            bf16x8 r0 = *(const bf16x8*)&Vp[(kv0 + 2 * kp) * 64 + d0];
            bf16x8 r1 = *(const bf16x8*)&Vp[(kv0 + 2 * kp + 1) * 64 + d0];
#pragma unroll
            for (int j = 0; j < 8; ++j)
                Vt32[(d0 + j) * 20 + kp] = (u32)(u16)r0[j] | ((u32)(u16)r1[j] << 16);
        }
        // QK^T: K fragments straight from global (L2-resident)
        f32x4 s0 = {0.f,0.f,0.f,0.f}, s1 = {0.f,0.f,0.f,0.f};
        {
            const u16* kb = &Kp[(kv0 + (lane & 15)) * 64 + (lane >> 4) * 8];
            bf16x8 k00 = *(const bf16x8*)(kb);
            bf16x8 k01 = *(const bf16x8*)(kb + 32);
            bf16x8 k10 = *(const bf16x8*)(kb + 16 * 64);
            bf16x8 k11 = *(const bf16x8*)(kb + 16 * 64 + 32);
            s0 = mfma16(aq[0], k00, s0); s0 = mfma16(aq[1], k01, s0);
            s1 = mfma16(aq[0], k10, s1); s1 = mfma16(aq[1], k11, s1);
        }
        // online softmax (rows (lane>>4)*4+j, key cols lane&15 / 16+lane&15)
#pragma unroll
        for (int j = 0; j < 4; ++j) {
            float tm = fmaxf(s0[j], s1[j]);
            tm = fmaxf(tm, __shfl_xor(tm, 1));
            tm = fmaxf(tm, __shfl_xor(tm, 2));
            tm = fmaxf(tm, __shfl_xor(tm, 4));
            tm = fmaxf(tm, __shfl_xor(tm, 8));
            const float mn = fmaxf(m[j], tm);
            const float corr = __expf(m[j] - mn);
            const float p0 = __expf(s0[j] - mn);
            const float p1 = __expf(s1[j] - mn);
            float rs = p0 + p1;
            rs += __shfl_xor(rs, 1); rs += __shfl_xor(rs, 2);
            rs += __shfl_xor(rs, 4); rs += __shfl_xor(rs, 8);
            l[j] = l[j] * corr + rs;
            m[j] = mn;
#pragma unroll
            for (int dt = 0; dt < 4; ++dt) o[dt][j] *= corr;
            const int pr = ((lane >> 4) << 2) + j;
            Pw[pr * 40 + (lane & 15)] = f2bf(p0);
            Pw[pr * 40 + 16 + (lane & 15)] = f2bf(p1);
        }
        __syncthreads();   // Vt + P visible
        // PV: out[16q x 64d] += P[16x32] * V[32x64]
        const bf16x8 pa = *(const bf16x8*)&Pw[(lane & 15) * 40 + (lane >> 4) * 8];
#pragma unroll
        for (int dt = 0; dt < 4; ++dt) {
            bf16x8 vbf = *(const bf16x8*)&Vt[(dt * 16 + (lane & 15)) * 40 + (lane >> 4) * 8];
            o[dt] = mfma16(pa, vbf, o[dt]);
        }
        __syncthreads();   // all reads done before next iter overwrites
    }

    const int b = bh / 12, h = bh - b * 12;
#pragma unroll
    for (int dt = 0; dt < 4; ++dt) {
#pragma unroll
        for (int j = 0; j < 4; ++j) {
            const int n = q0 + ((lane >> 4) << 2) + j;
            const float val = o[dt][j] / l[j];
            O[(size_t)((b << 10) + n) * 768 + h * 64 + dt * 16 + (lane & 15)] = f2bf(val);
        }
    }
}

extern "C" void kernel_launch(void* const* d_in, const int* in_sizes, int n_in,
                              void* d_out, int out_size, void* d_ws, size_t ws_size,
                              hipStream_t stream) {
    const float* x      = (const float*)d_in[0];   // [8,1024,768]
    const float* w_qkv  = (const float*)d_in[1];   // [2304,768]
    const float* q_bias = (const float*)d_in[2];   // [768]
    const float* v_bias = (const float*)d_in[3];   // [768]
    const float* w_proj = (const float*)d_in[4];   // [768,768]
    const float* b_proj = (const float*)d_in[5];   // [768]
    float* out = (float*)d_out;                    // [8,1024,768] fp32

    char* ws = (char*)d_ws;
    u16* xb     = (u16*)(ws);                       // 12,582,912 B
    u16* wqkvb  = (u16*)(ws + 12582912);            //  3,538,944 B
    u16* wprojb = (u16*)(ws + 16121856);            //  1,179,648 B
    u16* qw     = (u16*)(ws + 17301504);            // 12,582,912 B
    u16* kw     = (u16*)(ws + 29884416);            // 12,582,912 B
    u16* vw     = (u16*)(ws + 42467328);            // 12,582,912 B
    u16* ob     = (u16*)(ws + 55050240);            // 12,582,912 B  (end 67.6 MB)

    cvt_kernel<<<786432 / 256, 256, 0, stream>>>(x, xb, 786432);
    cvt_kernel<<<221184 / 256, 256, 0, stream>>>(w_qkv, wqkvb, 221184);
    cvt_kernel<<< 73728 / 256, 256, 0, stream>>>(w_proj, wprojb, 73728);

    gemm_bt<0><<<(8192 / 128) * (2304 / 128), 256, 0, stream>>>(
        xb, wqkvb, 8192, 2304, 768, qw, kw, vw, q_bias, v_bias, nullptr, nullptr);

    attn_fwd<<<96 * 16, 256, 0, stream>>>(qw, kw, vw, ob);

    gemm_bt<1><<<(8192 / 128) * (768 / 128), 256, 0, stream>>>(
        ob, wprojb, 8192, 768, 768, nullptr, nullptr, nullptr, nullptr, nullptr, out, b_proj);
}

// Round 2
// 173.289 us; speedup vs baseline: 1.2918x; 1.2918x over previous
//
#include <hip/hip_runtime.h>
#include <hip/hip_bf16.h>

typedef unsigned short u16;
typedef unsigned int u32;
typedef __attribute__((ext_vector_type(4))) float f32x4;
typedef __attribute__((ext_vector_type(16))) float f32x16;
typedef __attribute__((ext_vector_type(8))) short bf16x8;

__device__ inline u16 f2bf(float f) {
    union { float f; u32 u; } v; v.f = f;
    u32 r = v.u + 0x7fff + ((v.u >> 16) & 1);
    return (u16)(r >> 16);
}

__device__ inline f32x4 mfma16(bf16x8 a, bf16x8 b, f32x4 c) {
    return __builtin_amdgcn_mfma_f32_16x16x32_bf16(a, b, c, 0, 0, 0);
}
__device__ inline f32x16 mfma32(bf16x8 a, bf16x8 b, f32x16 c) {
    return __builtin_amdgcn_mfma_f32_32x32x16_bf16(a, b, c, 0, 0, 0);
}
__device__ inline u32 cvtpk(float lo, float hi) {
    u32 r;
    asm("v_cvt_pk_bf16_f32 %0, %1, %2" : "=v"(r) : "v"(lo), "v"(hi));
    return r;
}

__device__ inline void gload_lds16(const void* g, const void* l) {
    __builtin_amdgcn_global_load_lds(
        (const __attribute__((address_space(1))) void*)g,
        (__attribute__((address_space(3))) void*)l, 16, 0, 0);
}

// ---------------- fp32 -> bf16 conversion, 8 elems/thread ----------------
__global__ void cvt_kernel(const float* __restrict__ in, u16* __restrict__ out, int n8) {
    int i = blockIdx.x * 256 + threadIdx.x;
    if (i >= n8) return;
    const float4* p = (const float4*)in;
    float4 a = p[2 * i], b = p[2 * i + 1];
    bf16x8 v;
    v[0] = (short)f2bf(a.x); v[1] = (short)f2bf(a.y);
    v[2] = (short)f2bf(a.z); v[3] = (short)f2bf(a.w);
    v[4] = (short)f2bf(b.x); v[5] = (short)f2bf(b.y);
    v[6] = (short)f2bf(b.z); v[7] = (short)f2bf(b.w);
    ((bf16x8*)out)[i] = v;
}

// ---------------- GEMM  C[M,N] = A[M,K] * B[N,K]^T  (bf16 in, f32 acc) ---
// 128x128 tile, 4 waves (2x2 of 64x64), BK=32, 2-phase gload_lds dbuf.
// EPI 0: scatter q [bh][n][64]*0.125, k [bh][n][64], V TRANSPOSED vt[bh][d][n]
// EPI 1: fp32 out [M][N] + bias
template <int EPI>
__global__ __launch_bounds__(256) void gemm_bt(
    const u16* __restrict__ A, const u16* __restrict__ B,
    int M, int N, int K,
    u16* __restrict__ qw, u16* __restrict__ kw, u16* __restrict__ vw,
    const float* __restrict__ qb, const float* __restrict__ vb,
    float* __restrict__ outp, const float* __restrict__ bproj)
{
    __shared__ __align__(16) u16 lA[2][128 * 32];
    __shared__ __align__(16) u16 lB[2][128 * 32];
    const int tid = threadIdx.x;
    const int lane = tid & 63;
    const int wv = tid >> 6;
    const int nbn = N >> 7;
    const int bm = blockIdx.x / nbn, bn = blockIdx.x % nbn;
    const int row0 = bm << 7, col0 = bn << 7;

    const int c0 = tid, c1 = tid + 256;                 // 16B chunk ids
    const int ldsOff0 = (wv * 64) * 8;                  // ushort offset, wave-uniform
    const int ldsOff1 = (256 + wv * 64) * 8;

    f32x4 acc[4][4];
#pragma unroll
    for (int i = 0; i < 4; i++)
#pragma unroll
        for (int j = 0; j < 4; j++) acc[i][j] = (f32x4){0.f, 0.f, 0.f, 0.f};

    const int nT = K >> 5;

    auto stage = [&](int buf, int t) {
        const int k0 = t << 5;
        gload_lds16(&A[(size_t)(row0 + (c0 >> 2)) * K + k0 + (c0 & 3) * 8], &lA[buf][ldsOff0]);
        gload_lds16(&A[(size_t)(row0 + (c1 >> 2)) * K + k0 + (c1 & 3) * 8], &lA[buf][ldsOff1]);
        gload_lds16(&B[(size_t)(col0 + (c0 >> 2)) * K + k0 + (c0 & 3) * 8], &lB[buf][ldsOff0]);
        gload_lds16(&B[(size_t)(col0 + (c1 >> 2)) * K + k0 + (c1 & 3) * 8], &lB[buf][ldsOff1]);
    };

    const int wr = (wv >> 1) << 6;   // wave row offset 0/64
    const int wc = (wv & 1) << 6;    // wave col offset 0/64

    stage(0, 0);
    __syncthreads();
    for (int t = 0; t < nT; ++t) {
        if (t + 1 < nT) stage((t + 1) & 1, t + 1);
        const int buf = t & 1;
        const u16* As = &lA[buf][(wr + (lane & 15)) * 32 + ((lane >> 4) * 8)];
        const u16* Bs = &lB[buf][(wc + (lane & 15)) * 32 + ((lane >> 4) * 8)];
        bf16x8 af[4], bfr[4];
#pragma unroll
        for (int i = 0; i < 4; i++) af[i] = *(const bf16x8*)(As + i * 16 * 32);
#pragma unroll
        for (int i = 0; i < 4; i++) bfr[i] = *(const bf16x8*)(Bs + i * 16 * 32);
#pragma unroll
        for (int i = 0; i < 4; i++)
#pragma unroll
            for (int j = 0; j < 4; j++)
                acc[i][j] = mfma16(af[i], bfr[j], acc[i][j]);
        __syncthreads();
    }

    if (EPI == 0) {
#pragma unroll
        for (int nj = 0; nj < 4; ++nj) {
            const int col = col0 + wc + nj * 16 + (lane & 15);
            const int part = col / 768;
            const int rem = col - part * 768;
            const int h = rem >> 6, d = rem & 63;
            if (part == 2) {
                // V transposed: vt[(b*12+h)][d][n], packed 4-consecutive-n stores
                const float bias = vb[rem];
#pragma unroll
                for (int mi = 0; mi < 4; ++mi) {
                    const int rowb = row0 + wr + mi * 16 + ((lane >> 4) << 2);
                    const int bb = rowb >> 10, n = rowb & 1023;
                    ushort4 pk;
                    pk.x = f2bf(acc[mi][nj][0] + bias);
                    pk.y = f2bf(acc[mi][nj][1] + bias);
                    pk.z = f2bf(acc[mi][nj][2] + bias);
                    pk.w = f2bf(acc[mi][nj][3] + bias);
                    *(ushort4*)&vw[((size_t)((bb * 12 + h) * 64 + d) << 10) + n] = pk;
                }
            } else {
                const float bias = (part == 0) ? qb[rem] : 0.f;
                const float sc = (part == 0) ? 0.125f : 1.f;
                u16* dst = (part == 0) ? qw : kw;
#pragma unroll
                for (int mi = 0; mi < 4; ++mi) {
#pragma unroll
                    for (int j = 0; j < 4; ++j) {
                        const int row = row0 + wr + mi * 16 + ((lane >> 4) << 2) + j;
                        const int bb = row >> 10, n = row & 1023;
                        dst[(size_t)(((bb * 12 + h) << 10) + n) * 64 + d] =
                            f2bf((acc[mi][nj][j] + bias) * sc);
                    }
                }
            }
        }
    } else {
#pragma unroll
        for (int nj = 0; nj < 4; ++nj) {
            const int col = col0 + wc + nj * 16 + (lane & 15);
            const float bias = bproj[col];
#pragma unroll
            for (int mi = 0; mi < 4; ++mi) {
#pragma unroll
                for (int j = 0; j < 4; ++j) {
                    const int row = row0 + wr + mi * 16 + ((lane >> 4) << 2) + j;
                    outp[(size_t)row * N + col] = acc[mi][nj][j] + bias;
                }
            }
        }
    }
}

// ---------------- flash attention, swapped-operand 32x32 MFMA ------------
// 1 wave = 32 q-rows, 4 waves/block (independent; no barriers in kv loop).
// S^T = mfma32(K, Q): lane owns q = lane&31, 16 scores (half of 32 keys;
// partner lane^32 has the other half). Softmax in-register; P->bf16 via
// cvt_pk + permlane32_swap -> PV B-frags. V^T read from global (L2).
__global__ __launch_bounds__(256, 4) void attn_fwd(
    const u16* __restrict__ Q, const u16* __restrict__ K,
    const u16* __restrict__ VT, u16* __restrict__ O)
{
    __shared__ __align__(16) u16 tlds[4][32 * 68];   // output transpose, pad 68
    const int tid = threadIdx.x, lane = tid & 63, wv = tid >> 6;
    const int l31 = lane & 31, hi = lane >> 5;
    const int bh = blockIdx.x % 96;    // 96%8==0: one head -> one XCD
    const int qbk = blockIdx.x / 96;
    const int q0 = qbk * 128 + wv * 32;
    const size_t base = (size_t)bh << 16;
    const u16* Qp = Q + base;
    const u16* Kp = K + base;
    const u16* Vp = VT + base;

    bf16x8 qf0, qf1, qf2, qf3;
    {
        const u16* qrow = &Qp[(q0 + l31) * 64 + hi * 8];
        qf0 = *(const bf16x8*)(qrow);
        qf1 = *(const bf16x8*)(qrow + 16);
        qf2 = *(const bf16x8*)(qrow + 32);
        qf3 = *(const bf16x8*)(qrow + 48);
    }

    f32x16 ot0, ot1;
#pragma unroll
    for (int i = 0; i < 16; ++i) { ot0[i] = 0.f; ot1[i] = 0.f; }
    float m = -1e30f, l = 0.f;

    for (int kt = 0; kt < 32; ++kt) {
        const int kv0 = kt << 5;
        const u16* krow = &Kp[(kv0 + l31) * 64 + hi * 8];
        bf16x8 kf0 = *(const bf16x8*)(krow);
        bf16x8 kf1 = *(const bf16x8*)(krow + 16);
        bf16x8 kf2 = *(const bf16x8*)(krow + 32);
        bf16x8 kf3 = *(const bf16x8*)(krow + 48);
        f32x16 s;
#pragma unroll
        for (int i = 0; i < 16; ++i) s[i] = 0.f;
        s = mfma32(kf0, qf0, s);
        s = mfma32(kf1, qf1, s);
        s = mfma32(kf2, qf2, s);
        s = mfma32(kf3, qf3, s);
        // V^T fragments (issue early, consumed at PV; hides L2 latency)
        const u16* vrow = &Vp[(size_t)l31 * 1024 + kv0 + hi * 8];
        bf16x8 vf00 = *(const bf16x8*)(vrow);                 // d 0-31,  k 0-15
        bf16x8 vf01 = *(const bf16x8*)(vrow + 16);            // d 0-31,  k 16-31
        bf16x8 vf10 = *(const bf16x8*)(vrow + 32 * 1024);     // d 32-63, k 0-15
        bf16x8 vf11 = *(const bf16x8*)(vrow + 32 * 1024 + 16);
        // ---- online softmax, fully in-register ----
        float t0 = fmaxf(fmaxf(s[0], s[1]), fmaxf(s[2], s[3]));
        float t1 = fmaxf(fmaxf(s[4], s[5]), fmaxf(s[6], s[7]));
        float t2 = fmaxf(fmaxf(s[8], s[9]), fmaxf(s[10], s[11]));
        float t3 = fmaxf(fmaxf(s[12], s[13]), fmaxf(s[14], s[15]));
        float tmax = fmaxf(fmaxf(t0, t1), fmaxf(t2, t3));
        tmax = fmaxf(tmax, __shfl_xor(tmax, 32));
        if (!__all(tmax - m <= 8.f)) {   // defer-max (T13)
            const float nm = fmaxf(m, tmax);
            const float cr = __expf(m - nm);
#pragma unroll
            for (int i = 0; i < 16; ++i) { ot0[i] *= cr; ot1[i] *= cr; }
            l *= cr; m = nm;
        }
#pragma unroll
        for (int i = 0; i < 16; ++i) { float p = __expf(s[i] - m); s[i] = p; l += p; }
        // ---- P -> bf16 PV B-frags via cvt_pk + permlane32_swap (T12) ----
        u32 w0 = cvtpk(s[0],  s[1]),  w1 = cvtpk(s[2],  s[3]);
        u32 w2 = cvtpk(s[4],  s[5]),  w3 = cvtpk(s[6],  s[7]);
        u32 w4 = cvtpk(s[8],  s[9]),  w5 = cvtpk(s[10], s[11]);
        u32 w6 = cvtpk(s[12], s[13]), w7 = cvtpk(s[14], s[15]);
        asm("v_permlane32_swap_b32 %0, %1" : "+v"(w0), "+v"(w2));
        asm("v_permlane32_swap_b32 %0, %1" : "+v"(w1), "+v"(w3));
        asm("v_permlane32_swap_b32 %0, %1" : "+v"(w4), "+v"(w6));
        asm("v_permlane32_swap_b32 %0, %1" : "+v"(w5), "+v"(w7));
        union { u32 u[4]; bf16x8 v; } pb0, pb1;
        pb0.u[0] = w0; pb0.u[1] = w1; pb0.u[2] = w2; pb0.u[3] = w3;
        pb1.u[0] = w4; pb1.u[1] = w5; pb1.u[2] = w6; pb1.u[3] = w7;
        ot0 = mfma32(vf00, pb0.v, ot0);
        ot0 = mfma32(vf01, pb1.v, ot0);
        ot1 = mfma32(vf10, pb0.v, ot1);
        ot1 = mfma32(vf11, pb1.v, ot1);
    }
    const float lt = l + __shfl_xor(l, 32);
    const float inv = 1.f / lt;
    // ---- transpose O^T[d][q] -> O[q][d] via per-wave padded LDS ----
    u16* tw = &tlds[wv][0];
    u32* tw32 = (u32*)tw;
#pragma unroll
    for (int i = 0; i < 8; ++i) {
        const int dl = 2 * (i & 1) + 8 * (i >> 1) + 4 * hi;  // crow(2i,hi)
        tw32[(l31 * 68 + dl) >> 1]      = cvtpk(ot0[2 * i] * inv, ot0[2 * i + 1] * inv);
        tw32[(l31 * 68 + dl + 32) >> 1] = cvtpk(ot1[2 * i] * inv, ot1[2 * i + 1] * inv);
    }
    __syncthreads();
    const int b = bh / 12, h = bh - b * 12;
    const size_t obase = ((size_t)(b << 10) + q0) * 768 + h * 64 + (lane & 7) * 8;
#pragma unroll
    for (int it = 0; it < 4; ++it) {
        const int r = it * 8 + (lane >> 3);
        bf16x8 v = *(const bf16x8*)&tw[r * 68 + (lane & 7) * 8];
        *(bf16x8*)&O[obase + (size_t)r * 768] = v;
    }
}

extern "C" void kernel_launch(void* const* d_in, const int* in_sizes, int n_in,
                              void* d_out, int out_size, void* d_ws, size_t ws_size,
                              hipStream_t stream) {
    const float* x      = (const float*)d_in[0];   // [8,1024,768]
    const float* w_qkv  = (const float*)d_in[1];   // [2304,768]
    const float* q_bias = (const float*)d_in[2];   // [768]
    const float* v_bias = (const float*)d_in[3];   // [768]
    const float* w_proj = (const float*)d_in[4];   // [768,768]
    const float* b_proj = (const float*)d_in[5];   // [768]
    float* out = (float*)d_out;                    // [8,1024,768] fp32

    char* ws = (char*)d_ws;
    u16* xb     = (u16*)(ws);                       // 12,582,912 B
    u16* wqkvb  = (u16*)(ws + 12582912);            //  3,538,944 B
    u16* wprojb = (u16*)(ws + 16121856);            //  1,179,648 B
    u16* qw     = (u16*)(ws + 17301504);            // 12,582,912 B
    u16* kw     = (u16*)(ws + 29884416);            // 12,582,912 B
    u16* vt     = (u16*)(ws + 42467328);            // 12,582,912 B  (V^T [bh][64][1024])
    u16* ob     = (u16*)(ws + 55050240);            // 12,582,912 B  (end 67.6 MB)

    cvt_kernel<<<786432 / 256, 256, 0, stream>>>(x, xb, 786432);
    cvt_kernel<<<221184 / 256, 256, 0, stream>>>(w_qkv, wqkvb, 221184);
    cvt_kernel<<< 73728 / 256, 256, 0, stream>>>(w_proj, wprojb, 73728);

    gemm_bt<0><<<(8192 / 128) * (2304 / 128), 256, 0, stream>>>(
        xb, wqkvb, 8192, 2304, 768, qw, kw, vt, q_bias, v_bias, nullptr, nullptr);

    attn_fwd<<<96 * 8, 256, 0, stream>>>(qw, kw, vt, ob);

    gemm_bt<1><<<(8192 / 128) * (768 / 128), 256, 0, stream>>>(
        ob, wprojb, 8192, 768, 768, nullptr, nullptr, nullptr, nullptr, nullptr, out, b_proj);
}

// Round 3
// 172.439 us; speedup vs baseline: 1.2982x; 1.0049x over previous
//
#include <hip/hip_runtime.h>
#include <hip/hip_bf16.h>

typedef unsigned short u16;
typedef unsigned int u32;
typedef __attribute__((ext_vector_type(4))) float f32x4;
typedef __attribute__((ext_vector_type(16))) float f32x16;
typedef __attribute__((ext_vector_type(8))) short bf16x8;

__device__ inline u16 f2bf(float f) {
    union { float f; u32 u; } v; v.f = f;
    u32 r = v.u + 0x7fff + ((v.u >> 16) & 1);
    return (u16)(r >> 16);
}

__device__ inline f32x4 mfma16(bf16x8 a, bf16x8 b, f32x4 c) {
    return __builtin_amdgcn_mfma_f32_16x16x32_bf16(a, b, c, 0, 0, 0);
}
__device__ inline f32x16 mfma32(bf16x8 a, bf16x8 b, f32x16 c) {
    return __builtin_amdgcn_mfma_f32_32x32x16_bf16(a, b, c, 0, 0, 0);
}
__device__ inline u32 cvtpk(float lo, float hi) {
    u32 r;
    asm("v_cvt_pk_bf16_f32 %0, %1, %2" : "=v"(r) : "v"(lo), "v"(hi));
    return r;
}
__device__ inline float exp2v(float x) {   // v_exp_f32: D = 2^S0 (TRANS pipe)
    float r;
    asm("v_exp_f32 %0, %1" : "=v"(r) : "v"(x));
    return r;
}

__device__ inline void gload_lds16(const void* g, const void* l) {
    __builtin_amdgcn_global_load_lds(
        (const __attribute__((address_space(1))) void*)g,
        (__attribute__((address_space(3))) void*)l, 16, 0, 0);
}

// log2(e) * head_dim^-0.5 — folded into q in the QKV epilogue (base-2 softmax)
#define QSCALE 0.18033688f

// ---------------- fp32 -> bf16 conversion, 8 elems/thread ----------------
__global__ void cvt_kernel(const float* __restrict__ in, u16* __restrict__ out, int n8) {
    int i = blockIdx.x * 256 + threadIdx.x;
    if (i >= n8) return;
    const float4* p = (const float4*)in;
    float4 a = p[2 * i], b = p[2 * i + 1];
    bf16x8 v;
    v[0] = (short)f2bf(a.x); v[1] = (short)f2bf(a.y);
    v[2] = (short)f2bf(a.z); v[3] = (short)f2bf(a.w);
    v[4] = (short)f2bf(b.x); v[5] = (short)f2bf(b.y);
    v[6] = (short)f2bf(b.z); v[7] = (short)f2bf(b.w);
    ((bf16x8*)out)[i] = v;
}

// ---------------- GEMM  C[M,N] = A[M,K] * B[N,K]^T  (bf16 in, f32 acc) ---
// 128x128 tile, 4 waves (2x2 of 64x64), BK=32, 2-phase gload_lds dbuf.
// EPI 0: scatter q [bh][n][64]*QSCALE, k [bh][n][64], V^T vt[bh][d][n]
// EPI 1: fp32 out [M][N] + bias
template <int EPI>
__global__ __launch_bounds__(256) void gemm_bt(
    const u16* __restrict__ A, const u16* __restrict__ B,
    int M, int N, int K,
    u16* __restrict__ qw, u16* __restrict__ kw, u16* __restrict__ vw,
    const float* __restrict__ qb, const float* __restrict__ vb,
    float* __restrict__ outp, const float* __restrict__ bproj)
{
    __shared__ __align__(16) u16 lA[2][128 * 32];
    __shared__ __align__(16) u16 lB[2][128 * 32];
    const int tid = threadIdx.x;
    const int lane = tid & 63;
    const int wv = tid >> 6;
    const int nbn = N >> 7;
    const int bm = blockIdx.x / nbn, bn = blockIdx.x % nbn;
    const int row0 = bm << 7, col0 = bn << 7;

    const int c0 = tid, c1 = tid + 256;                 // 16B chunk ids
    const int ldsOff0 = (wv * 64) * 8;                  // ushort offset, wave-uniform
    const int ldsOff1 = (256 + wv * 64) * 8;

    f32x4 acc[4][4];
#pragma unroll
    for (int i = 0; i < 4; i++)
#pragma unroll
        for (int j = 0; j < 4; j++) acc[i][j] = (f32x4){0.f, 0.f, 0.f, 0.f};

    const int nT = K >> 5;

    auto stage = [&](int buf, int t) {
        const int k0 = t << 5;
        gload_lds16(&A[(size_t)(row0 + (c0 >> 2)) * K + k0 + (c0 & 3) * 8], &lA[buf][ldsOff0]);
        gload_lds16(&A[(size_t)(row0 + (c1 >> 2)) * K + k0 + (c1 & 3) * 8], &lA[buf][ldsOff1]);
        gload_lds16(&B[(size_t)(col0 + (c0 >> 2)) * K + k0 + (c0 & 3) * 8], &lB[buf][ldsOff0]);
        gload_lds16(&B[(size_t)(col0 + (c1 >> 2)) * K + k0 + (c1 & 3) * 8], &lB[buf][ldsOff1]);
    };

    const int wr = (wv >> 1) << 6;   // wave row offset 0/64
    const int wc = (wv & 1) << 6;    // wave col offset 0/64

    stage(0, 0);
    __syncthreads();
    for (int t = 0; t < nT; ++t) {
        if (t + 1 < nT) stage((t + 1) & 1, t + 1);
        const int buf = t & 1;
        const u16* As = &lA[buf][(wr + (lane & 15)) * 32 + ((lane >> 4) * 8)];
        const u16* Bs = &lB[buf][(wc + (lane & 15)) * 32 + ((lane >> 4) * 8)];
        bf16x8 af[4], bfr[4];
#pragma unroll
        for (int i = 0; i < 4; i++) af[i] = *(const bf16x8*)(As + i * 16 * 32);
#pragma unroll
        for (int i = 0; i < 4; i++) bfr[i] = *(const bf16x8*)(Bs + i * 16 * 32);
#pragma unroll
        for (int i = 0; i < 4; i++)
#pragma unroll
            for (int j = 0; j < 4; j++)
                acc[i][j] = mfma16(af[i], bfr[j], acc[i][j]);
        __syncthreads();
    }

    if (EPI == 0) {
#pragma unroll
        for (int nj = 0; nj < 4; ++nj) {
            const int col = col0 + wc + nj * 16 + (lane & 15);
            const int part = col / 768;
            const int rem = col - part * 768;
            const int h = rem >> 6, d = rem & 63;
            if (part == 2) {
                // V transposed: vt[(b*12+h)][d][n], packed 4-consecutive-n stores
                const float bias = vb[rem];
#pragma unroll
                for (int mi = 0; mi < 4; ++mi) {
                    const int rowb = row0 + wr + mi * 16 + ((lane >> 4) << 2);
                    const int bb = rowb >> 10, n = rowb & 1023;
                    ushort4 pk;
                    pk.x = f2bf(acc[mi][nj][0] + bias);
                    pk.y = f2bf(acc[mi][nj][1] + bias);
                    pk.z = f2bf(acc[mi][nj][2] + bias);
                    pk.w = f2bf(acc[mi][nj][3] + bias);
                    *(ushort4*)&vw[((size_t)((bb * 12 + h) * 64 + d) << 10) + n] = pk;
                }
            } else {
                const float bias = (part == 0) ? qb[rem] : 0.f;
                const float sc = (part == 0) ? QSCALE : 1.f;
                u16* dst = (part == 0) ? qw : kw;
#pragma unroll
                for (int mi = 0; mi < 4; ++mi) {
#pragma unroll
                    for (int j = 0; j < 4; ++j) {
                        const int row = row0 + wr + mi * 16 + ((lane >> 4) << 2) + j;
                        const int bb = row >> 10, n = row & 1023;
                        dst[(size_t)(((bb * 12 + h) << 10) + n) * 64 + d] =
                            f2bf((acc[mi][nj][j] + bias) * sc);
                    }
                }
            }
        }
    } else {
#pragma unroll
        for (int nj = 0; nj < 4; ++nj) {
            const int col = col0 + wc + nj * 16 + (lane & 15);
            const float bias = bproj[col];
#pragma unroll
            for (int mi = 0; mi < 4; ++mi) {
#pragma unroll
                for (int j = 0; j < 4; ++j) {
                    const int row = row0 + wr + mi * 16 + ((lane >> 4) << 2) + j;
                    outp[(size_t)row * N + col] = acc[mi][nj][j] + bias;
                }
            }
        }
    }
}

// ---------------- flash attention, swapped-operand 32x32 MFMA ------------
// 1 wave = 32 q-rows, 4 waves/block, no barriers in kv loop.
// K(t+1) prefetched into a second register set (2x manual unroll).
// Softmax in base-2 domain (scale*log2e folded into q). V^T from global L2.
__global__ __launch_bounds__(256, 3) void attn_fwd(
    const u16* __restrict__ Q, const u16* __restrict__ K,
    const u16* __restrict__ VT, u16* __restrict__ O)
{
    __shared__ __align__(16) u16 tlds[4][32 * 68];   // output transpose, pad 68
    const int tid = threadIdx.x, lane = tid & 63, wv = tid >> 6;
    const int l31 = lane & 31, hi = lane >> 5;
    const int bh = blockIdx.x % 96;    // 96%8==0: one head -> one XCD
    const int qbk = blockIdx.x / 96;
    const int q0 = qbk * 128 + wv * 32;
    const size_t base = (size_t)bh << 16;
    const u16* Qp = Q + base;
    const u16* Kp = K + base;
    const u16* Vp = VT + base;

    bf16x8 qf0, qf1, qf2, qf3;
    {
        const u16* qrow = &Qp[(q0 + l31) * 64 + hi * 8];
        qf0 = *(const bf16x8*)(qrow);
        qf1 = *(const bf16x8*)(qrow + 16);
        qf2 = *(const bf16x8*)(qrow + 32);
        qf3 = *(const bf16x8*)(qrow + 48);
    }

    f32x16 ot0, ot1;
#pragma unroll
    for (int i = 0; i < 16; ++i) { ot0[i] = 0.f; ot1[i] = 0.f; }
    float m = -1e30f, l = 0.f;

    auto loadK = [&](int kv0, bf16x8& f0, bf16x8& f1, bf16x8& f2, bf16x8& f3) {
        const u16* kr = &Kp[(kv0 + l31) * 64 + hi * 8];
        f0 = *(const bf16x8*)(kr);
        f1 = *(const bf16x8*)(kr + 16);
        f2 = *(const bf16x8*)(kr + 32);
        f3 = *(const bf16x8*)(kr + 48);
    };

    auto body = [&](int kv0, bf16x8 k0, bf16x8 k1, bf16x8 k2, bf16x8 k3) {
        f32x16 s;
#pragma unroll
        for (int i = 0; i < 16; ++i) s[i] = 0.f;
        __builtin_amdgcn_s_setprio(1);
        s = mfma32(k0, qf0, s);
        s = mfma32(k1, qf1, s);
        s = mfma32(k2, qf2, s);
        s = mfma32(k3, qf3, s);
        __builtin_amdgcn_s_setprio(0);
        // V^T fragments: issue now, consumed after softmax (latency hidden)
        const u16* vrow = &Vp[(size_t)l31 * 1024 + kv0 + hi * 8];
        bf16x8 vf00 = *(const bf16x8*)(vrow);                 // d 0-31,  k 0-15
        bf16x8 vf01 = *(const bf16x8*)(vrow + 16);            // d 0-31,  k 16-31
        bf16x8 vf10 = *(const bf16x8*)(vrow + 32 * 1024);     // d 32-63, k 0-15
        bf16x8 vf11 = *(const bf16x8*)(vrow + 32 * 1024 + 16);
        // ---- online softmax (base-2), fully in-register ----
        float t0 = fmaxf(fmaxf(s[0], s[1]), fmaxf(s[2], s[3]));
        float t1 = fmaxf(fmaxf(s[4], s[5]), fmaxf(s[6], s[7]));
        float t2 = fmaxf(fmaxf(s[8], s[9]), fmaxf(s[10], s[11]));
        float t3 = fmaxf(fmaxf(s[12], s[13]), fmaxf(s[14], s[15]));
        float tmax = fmaxf(fmaxf(t0, t1), fmaxf(t2, t3));
        tmax = fmaxf(tmax, __shfl_xor(tmax, 32));
        if (!__all(tmax - m <= 8.f)) {   // defer-max (T13), 2^8 headroom
            const float nm = fmaxf(m, tmax);
            const float cr = exp2v(m - nm);
#pragma unroll
            for (int i = 0; i < 16; ++i) { ot0[i] *= cr; ot1[i] *= cr; }
            l *= cr; m = nm;
        }
#pragma unroll
        for (int i = 0; i < 16; ++i) { float p = exp2v(s[i] - m); s[i] = p; l += p; }
        // ---- P -> bf16 PV B-frags via cvt_pk + permlane32_swap (T12) ----
        u32 w0 = cvtpk(s[0],  s[1]),  w1 = cvtpk(s[2],  s[3]);
        u32 w2 = cvtpk(s[4],  s[5]),  w3 = cvtpk(s[6],  s[7]);
        u32 w4 = cvtpk(s[8],  s[9]),  w5 = cvtpk(s[10], s[11]);
        u32 w6 = cvtpk(s[12], s[13]), w7 = cvtpk(s[14], s[15]);
        asm("v_permlane32_swap_b32 %0, %1" : "+v"(w0), "+v"(w2));
        asm("v_permlane32_swap_b32 %0, %1" : "+v"(w1), "+v"(w3));
        asm("v_permlane32_swap_b32 %0, %1" : "+v"(w4), "+v"(w6));
        asm("v_permlane32_swap_b32 %0, %1" : "+v"(w5), "+v"(w7));
        union { u32 u[4]; bf16x8 v; } pb0, pb1;
        pb0.u[0] = w0; pb0.u[1] = w1; pb0.u[2] = w2; pb0.u[3] = w3;
        pb1.u[0] = w4; pb1.u[1] = w5; pb1.u[2] = w6; pb1.u[3] = w7;
        __builtin_amdgcn_s_setprio(1);
        ot0 = mfma32(vf00, pb0.v, ot0);
        ot0 = mfma32(vf01, pb1.v, ot0);
        ot1 = mfma32(vf10, pb0.v, ot1);
        ot1 = mfma32(vf11, pb1.v, ot1);
        __builtin_amdgcn_s_setprio(0);
    };

    bf16x8 ka0, ka1, ka2, ka3, kb0, kb1, kb2, kb3;
    loadK(0, ka0, ka1, ka2, ka3);
    for (int kt = 0; kt < 32; kt += 2) {
        loadK((kt + 1) << 5, kb0, kb1, kb2, kb3);   // prefetch t+1
        body(kt << 5, ka0, ka1, ka2, ka3);
        if (kt + 2 < 32) loadK((kt + 2) << 5, ka0, ka1, ka2, ka3);  // prefetch t+2
        body((kt + 1) << 5, kb0, kb1, kb2, kb3);
    }

    const float lt = l + __shfl_xor(l, 32);
    const float inv = 1.f / lt;
    // ---- transpose O^T[d][q] -> O[q][d] via per-wave padded LDS ----
    u16* tw = &tlds[wv][0];
    u32* tw32 = (u32*)tw;
#pragma unroll
    for (int i = 0; i < 8; ++i) {
        const int dl = 2 * (i & 1) + 8 * (i >> 1) + 4 * hi;  // crow(2i,hi)
        tw32[(l31 * 68 + dl) >> 1]      = cvtpk(ot0[2 * i] * inv, ot0[2 * i + 1] * inv);
        tw32[(l31 * 68 + dl + 32) >> 1] = cvtpk(ot1[2 * i] * inv, ot1[2 * i + 1] * inv);
    }
    __syncthreads();
    const int b = bh / 12, h = bh - b * 12;
    const size_t obase = ((size_t)(b << 10) + q0) * 768 + h * 64 + (lane & 7) * 8;
#pragma unroll
    for (int it = 0; it < 4; ++it) {
        const int r = it * 8 + (lane >> 3);
        bf16x8 v = *(const bf16x8*)&tw[r * 68 + (lane & 7) * 8];
        *(bf16x8*)&O[obase + (size_t)r * 768] = v;
    }
}

extern "C" void kernel_launch(void* const* d_in, const int* in_sizes, int n_in,
                              void* d_out, int out_size, void* d_ws, size_t ws_size,
                              hipStream_t stream) {
    const float* x      = (const float*)d_in[0];   // [8,1024,768]
    const float* w_qkv  = (const float*)d_in[1];   // [2304,768]
    const float* q_bias = (const float*)d_in[2];   // [768]
    const float* v_bias = (const float*)d_in[3];   // [768]
    const float* w_proj = (const float*)d_in[4];   // [768,768]
    const float* b_proj = (const float*)d_in[5];   // [768]
    float* out = (float*)d_out;                    // [8,1024,768] fp32

    char* ws = (char*)d_ws;
    u16* xb     = (u16*)(ws);                       // 12,582,912 B
    u16* wqkvb  = (u16*)(ws + 12582912);            //  3,538,944 B
    u16* wprojb = (u16*)(ws + 16121856);            //  1,179,648 B
    u16* qw     = (u16*)(ws + 17301504);            // 12,582,912 B
    u16* kw     = (u16*)(ws + 29884416);            // 12,582,912 B
    u16* vt     = (u16*)(ws + 42467328);            // 12,582,912 B  (V^T [bh][64][1024])
    u16* ob     = (u16*)(ws + 55050240);            // 12,582,912 B  (end 67.6 MB)

    cvt_kernel<<<786432 / 256, 256, 0, stream>>>(x, xb, 786432);
    cvt_kernel<<<221184 / 256, 256, 0, stream>>>(w_qkv, wqkvb, 221184);
    cvt_kernel<<< 73728 / 256, 256, 0, stream>>>(w_proj, wprojb, 73728);

    gemm_bt<0><<<(8192 / 128) * (2304 / 128), 256, 0, stream>>>(
        xb, wqkvb, 8192, 2304, 768, qw, kw, vt, q_bias, v_bias, nullptr, nullptr);

    attn_fwd<<<96 * 8, 256, 0, stream>>>(qw, kw, vt, ob);

    gemm_bt<1><<<(8192 / 128) * (768 / 128), 256, 0, stream>>>(
        ob, wprojb, 8192, 768, 768, nullptr, nullptr, nullptr, nullptr, nullptr, out, b_proj);
}

// Round 4
// 129.291 us; speedup vs baseline: 1.7315x; 1.3337x over previous
//
#include <hip/hip_runtime.h>
#include <hip/hip_bf16.h>

typedef unsigned short u16;
typedef unsigned int u32;
typedef __attribute__((ext_vector_type(4))) float f32x4;
typedef __attribute__((ext_vector_type(16))) float f32x16;
typedef __attribute__((ext_vector_type(8))) short bf16x8;

__device__ inline u16 f2bf(float f) {
    union { float f; u32 u; } v; v.f = f;
    u32 r = v.u + 0x7fff + ((v.u >> 16) & 1);
    return (u16)(r >> 16);
}

__device__ inline f32x4 mfma16(bf16x8 a, bf16x8 b, f32x4 c) {
    return __builtin_amdgcn_mfma_f32_16x16x32_bf16(a, b, c, 0, 0, 0);
}
__device__ inline f32x16 mfma32(bf16x8 a, bf16x8 b, f32x16 c) {
    return __builtin_amdgcn_mfma_f32_32x32x16_bf16(a, b, c, 0, 0, 0);
}
__device__ inline u32 cvtpk(float lo, float hi) {
    u32 r;
    asm("v_cvt_pk_bf16_f32 %0, %1, %2" : "=v"(r) : "v"(lo), "v"(hi));
    return r;
}
__device__ inline float exp2v(float x) {   // v_exp_f32: D = 2^S0 (TRANS pipe)
    float r;
    asm("v_exp_f32 %0, %1" : "=v"(r) : "v"(x));
    return r;
}

__device__ inline void gload_lds16(const void* g, const void* l) {
    __builtin_amdgcn_global_load_lds(
        (const __attribute__((address_space(1))) void*)g,
        (__attribute__((address_space(3))) void*)l, 16, 0, 0);
}

// log2(e) * head_dim^-0.5 — folded into q in the QKV epilogue (base-2 softmax)
#define QSCALE 0.18033688f

// ---------------- fp32 -> bf16 conversion, 8 elems/thread ----------------
__global__ void cvt_kernel(const float* __restrict__ in, u16* __restrict__ out, int n8) {
    int i = blockIdx.x * 256 + threadIdx.x;
    if (i >= n8) return;
    const float4* p = (const float4*)in;
    float4 a = p[2 * i], b = p[2 * i + 1];
    bf16x8 v;
    v[0] = (short)f2bf(a.x); v[1] = (short)f2bf(a.y);
    v[2] = (short)f2bf(a.z); v[3] = (short)f2bf(a.w);
    v[4] = (short)f2bf(b.x); v[5] = (short)f2bf(b.y);
    v[6] = (short)f2bf(b.z); v[7] = (short)f2bf(b.w);
    ((bf16x8*)out)[i] = v;
}

// ---------------- GEMM  C[M,N] = A[M,K] * B[N,K]^T  (bf16 in, f32 acc) ---
// 128x128 tile, 4 waves (2x2 of 64x64), BK=32, 2-phase gload_lds dbuf.
// EPI 0: q row-major [bh][n][64]*QSCALE; K,V in MFMA-FRAGMENT ORDER:
//   Kf: elem(n,d) -> (bh<<16) + (n>>5)*2048 + (d>>3)*256 + (n&31)*8 + (d&7)
//   Vf: elem(n,d) -> (bh<<16) + (n>>5)*2048 + ((d>>5)*2+((n&31)>>4))*512
//                    + (((n>>3)&1)*32 + (d&31))*8 + (n&7)
// EPI 1: fp32 out [M][N] + bias
template <int EPI>
__global__ __launch_bounds__(256) void gemm_bt(
    const u16* __restrict__ A, const u16* __restrict__ B,
    int M, int N, int K,
    u16* __restrict__ qw, u16* __restrict__ kw, u16* __restrict__ vw,
    const float* __restrict__ qb, const float* __restrict__ vb,
    float* __restrict__ outp, const float* __restrict__ bproj)
{
    __shared__ __align__(16) u16 lA[2][128 * 32];
    __shared__ __align__(16) u16 lB[2][128 * 32];
    const int tid = threadIdx.x;
    const int lane = tid & 63;
    const int wv = tid >> 6;
    const int nbn = N >> 7;
    const int bm = blockIdx.x / nbn, bn = blockIdx.x % nbn;
    const int row0 = bm << 7, col0 = bn << 7;

    const int c0 = tid, c1 = tid + 256;                 // 16B chunk ids
    const int ldsOff0 = (wv * 64) * 8;                  // ushort offset, wave-uniform
    const int ldsOff1 = (256 + wv * 64) * 8;

    f32x4 acc[4][4];
#pragma unroll
    for (int i = 0; i < 4; i++)
#pragma unroll
        for (int j = 0; j < 4; j++) acc[i][j] = (f32x4){0.f, 0.f, 0.f, 0.f};

    const int nT = K >> 5;

    auto stage = [&](int buf, int t) {
        const int k0 = t << 5;
        gload_lds16(&A[(size_t)(row0 + (c0 >> 2)) * K + k0 + (c0 & 3) * 8], &lA[buf][ldsOff0]);
        gload_lds16(&A[(size_t)(row0 + (c1 >> 2)) * K + k0 + (c1 & 3) * 8], &lA[buf][ldsOff1]);
        gload_lds16(&B[(size_t)(col0 + (c0 >> 2)) * K + k0 + (c0 & 3) * 8], &lB[buf][ldsOff0]);
        gload_lds16(&B[(size_t)(col0 + (c1 >> 2)) * K + k0 + (c1 & 3) * 8], &lB[buf][ldsOff1]);
    };

    const int wr = (wv >> 1) << 6;   // wave row offset 0/64
    const int wc = (wv & 1) << 6;    // wave col offset 0/64

    stage(0, 0);
    __syncthreads();
    for (int t = 0; t < nT; ++t) {
        if (t + 1 < nT) stage((t + 1) & 1, t + 1);
        const int buf = t & 1;
        const u16* As = &lA[buf][(wr + (lane & 15)) * 32 + ((lane >> 4) * 8)];
        const u16* Bs = &lB[buf][(wc + (lane & 15)) * 32 + ((lane >> 4) * 8)];
        bf16x8 af[4], bfr[4];
#pragma unroll
        for (int i = 0; i < 4; i++) af[i] = *(const bf16x8*)(As + i * 16 * 32);
#pragma unroll
        for (int i = 0; i < 4; i++) bfr[i] = *(const bf16x8*)(Bs + i * 16 * 32);
#pragma unroll
        for (int i = 0; i < 4; i++)
#pragma unroll
            for (int j = 0; j < 4; j++)
                acc[i][j] = mfma16(af[i], bfr[j], acc[i][j]);
        __syncthreads();
    }

    if (EPI == 0) {
#pragma unroll
        for (int nj = 0; nj < 4; ++nj) {
            const int col = col0 + wc + nj * 16 + (lane & 15);
            const int part = col / 768;
            const int rem = col - part * 768;
            const int h = rem >> 6, d = rem & 63;
            if (part == 2) {
                // V fragment-order: 4 consecutive n -> one ushort4
                const float bias = vb[rem];
                const int fbase = ((d >> 5) << 1);
                const int dl = d & 31;
#pragma unroll
                for (int mi = 0; mi < 4; ++mi) {
                    const int rowb = row0 + wr + mi * 16 + ((lane >> 4) << 2);
                    const int bb = rowb >> 10, nb = rowb & 1023;
                    const int t2 = nb >> 5, kin = nb & 31;
                    const int f = fbase + (kin >> 4);
                    const int lane_ = (((kin >> 3) & 1) << 5) + dl;
                    ushort4 pk;
                    pk.x = f2bf(acc[mi][nj][0] + bias);
                    pk.y = f2bf(acc[mi][nj][1] + bias);
                    pk.z = f2bf(acc[mi][nj][2] + bias);
                    pk.w = f2bf(acc[mi][nj][3] + bias);
                    *(ushort4*)&vw[((size_t)(bb * 12 + h) << 16) + (t2 << 11) +
                                   (f << 9) + (lane_ << 3) + (nb & 7)] = pk;
                }
            } else if (part == 1) {
                // K fragment-order, scalar scatter
                const int joff = (d >> 3) << 8, e = d & 7;
#pragma unroll
                for (int mi = 0; mi < 4; ++mi) {
#pragma unroll
                    for (int j = 0; j < 4; ++j) {
                        const int row = row0 + wr + mi * 16 + ((lane >> 4) << 2) + j;
                        const int bb = row >> 10, n = row & 1023;
                        kw[((size_t)(bb * 12 + h) << 16) + ((n >> 5) << 11) + joff +
                           ((n & 31) << 3) + e] = f2bf(acc[mi][nj][j]);
                    }
                }
            } else {
                // Q row-major [bh][n][64], scaled
                const float bias = qb[rem];
#pragma unroll
                for (int mi = 0; mi < 4; ++mi) {
#pragma unroll
                    for (int j = 0; j < 4; ++j) {
                        const int row = row0 + wr + mi * 16 + ((lane >> 4) << 2) + j;
                        const int bb = row >> 10, n = row & 1023;
                        qw[(size_t)(((bb * 12 + h) << 10) + n) * 64 + d] =
                            f2bf((acc[mi][nj][j] + bias) * QSCALE);
                    }
                }
            }
        }
    } else {
#pragma unroll
        for (int nj = 0; nj < 4; ++nj) {
            const int col = col0 + wc + nj * 16 + (lane & 15);
            const float bias = bproj[col];
#pragma unroll
            for (int mi = 0; mi < 4; ++mi) {
#pragma unroll
                for (int j = 0; j < 4; ++j) {
                    const int row = row0 + wr + mi * 16 + ((lane >> 4) << 2) + j;
                    outp[(size_t)row * N + col] = acc[mi][nj][j] + bias;
                }
            }
        }
    }
}

// ---------------- flash attention, swapped-operand 32x32 MFMA ------------
// 1 wave = 32 q-rows, 4 waves/block, no barriers in kv loop.
// K and V read from FRAGMENT-ORDER global layouts: every load instruction
// is a contiguous 1KB (8 fully-used cache lines) instead of 32 scattered
// lines. K(t+1) prefetched into a second register set (2x manual unroll).
__global__ __launch_bounds__(256, 3) void attn_fwd(
    const u16* __restrict__ Q, const u16* __restrict__ KF,
    const u16* __restrict__ VF, u16* __restrict__ O)
{
    __shared__ __align__(16) u16 tlds[4][32 * 68];   // output transpose, pad 68
    const int tid = threadIdx.x, lane = tid & 63, wv = tid >> 6;
    const int l31 = lane & 31, hi = lane >> 5;
    const int bh = blockIdx.x % 96;    // 96%8==0: one head -> one XCD
    const int qbk = blockIdx.x / 96;
    const int q0 = qbk * 128 + wv * 32;
    const size_t base = (size_t)bh << 16;
    const u16* Qp = Q + base;
    const u16* Kp = KF + base;
    const u16* Vp = VF + base;

    bf16x8 qf0, qf1, qf2, qf3;
    {
        const u16* qrow = &Qp[(q0 + l31) * 64 + hi * 8];
        qf0 = *(const bf16x8*)(qrow);
        qf1 = *(const bf16x8*)(qrow + 16);
        qf2 = *(const bf16x8*)(qrow + 32);
        qf3 = *(const bf16x8*)(qrow + 48);
    }

    f32x16 ot0, ot1;
#pragma unroll
    for (int i = 0; i < 16; ++i) { ot0[i] = 0.f; ot1[i] = 0.f; }
    float m = -1e30f, l = 0.f;

    // Kf tile t: chunk j=2i+hi at t*2048 + (2i+hi)*256 + l31*8
    auto loadK = [&](int t2048, bf16x8& f0, bf16x8& f1, bf16x8& f2, bf16x8& f3) {
        const u16* kr = &Kp[t2048 + hi * 256 + l31 * 8];
        f0 = *(const bf16x8*)(kr);
        f1 = *(const bf16x8*)(kr + 512);
        f2 = *(const bf16x8*)(kr + 1024);
        f3 = *(const bf16x8*)(kr + 1536);
    };

    auto body = [&](int t2048, bf16x8 k0, bf16x8 k1, bf16x8 k2, bf16x8 k3) {
        f32x16 s;
#pragma unroll
        for (int i = 0; i < 16; ++i) s[i] = 0.f;
        __builtin_amdgcn_s_setprio(1);
        s = mfma32(k0, qf0, s);
        s = mfma32(k1, qf1, s);
        s = mfma32(k2, qf2, s);
        s = mfma32(k3, qf3, s);
        __builtin_amdgcn_s_setprio(0);
        // V fragments: contiguous 1KB each, issued before softmax
        const u16* vrow = &Vp[t2048 + lane * 8];
        bf16x8 vf00 = *(const bf16x8*)(vrow);           // f=0: d 0-31,  k 0-15
        bf16x8 vf01 = *(const bf16x8*)(vrow + 512);     // f=1: d 0-31,  k 16-31
        bf16x8 vf10 = *(const bf16x8*)(vrow + 1024);    // f=2: d 32-63, k 0-15
        bf16x8 vf11 = *(const bf16x8*)(vrow + 1536);    // f=3: d 32-63, k 16-31
        // ---- online softmax (base-2), fully in-register ----
        float t0 = fmaxf(fmaxf(s[0], s[1]), fmaxf(s[2], s[3]));
        float t1 = fmaxf(fmaxf(s[4], s[5]), fmaxf(s[6], s[7]));
        float t2 = fmaxf(fmaxf(s[8], s[9]), fmaxf(s[10], s[11]));
        float t3 = fmaxf(fmaxf(s[12], s[13]), fmaxf(s[14], s[15]));
        float tmax = fmaxf(fmaxf(t0, t1), fmaxf(t2, t3));
        tmax = fmaxf(tmax, __shfl_xor(tmax, 32));
        if (!__all(tmax - m <= 8.f)) {   // defer-max (T13), 2^8 headroom
            const float nm = fmaxf(m, tmax);
            const float cr = exp2v(m - nm);
#pragma unroll
            for (int i = 0; i < 16; ++i) { ot0[i] *= cr; ot1[i] *= cr; }
            l *= cr; m = nm;
        }
#pragma unroll
        for (int i = 0; i < 16; ++i) { float p = exp2v(s[i] - m); s[i] = p; l += p; }
        // ---- P -> bf16 PV B-frags via cvt_pk + permlane32_swap (T12) ----
        u32 w0 = cvtpk(s[0],  s[1]),  w1 = cvtpk(s[2],  s[3]);
        u32 w2 = cvtpk(s[4],  s[5]),  w3 = cvtpk(s[6],  s[7]);
        u32 w4 = cvtpk(s[8],  s[9]),  w5 = cvtpk(s[10], s[11]);
        u32 w6 = cvtpk(s[12], s[13]), w7 = cvtpk(s[14], s[15]);
        asm("v_permlane32_swap_b32 %0, %1" : "+v"(w0), "+v"(w2));
        asm("v_permlane32_swap_b32 %0, %1" : "+v"(w1), "+v"(w3));
        asm("v_permlane32_swap_b32 %0, %1" : "+v"(w4), "+v"(w6));
        asm("v_permlane32_swap_b32 %0, %1" : "+v"(w5), "+v"(w7));
        union { u32 u[4]; bf16x8 v; } pb0, pb1;
        pb0.u[0] = w0; pb0.u[1] = w1; pb0.u[2] = w2; pb0.u[3] = w3;
        pb1.u[0] = w4; pb1.u[1] = w5; pb1.u[2] = w6; pb1.u[3] = w7;
        __builtin_amdgcn_s_setprio(1);
        ot0 = mfma32(vf00, pb0.v, ot0);
        ot0 = mfma32(vf01, pb1.v, ot0);
        ot1 = mfma32(vf10, pb0.v, ot1);
        ot1 = mfma32(vf11, pb1.v, ot1);
        __builtin_amdgcn_s_setprio(0);
    };

    bf16x8 ka0, ka1, ka2, ka3, kb0, kb1, kb2, kb3;
    loadK(0, ka0, ka1, ka2, ka3);
    for (int kt = 0; kt < 32; kt += 2) {
        loadK((kt + 1) << 11, kb0, kb1, kb2, kb3);   // prefetch t+1
        body(kt << 11, ka0, ka1, ka2, ka3);
        if (kt + 2 < 32) loadK((kt + 2) << 11, ka0, ka1, ka2, ka3);  // prefetch t+2
        body((kt + 1) << 11, kb0, kb1, kb2, kb3);
    }

    const float lt = l + __shfl_xor(l, 32);
    const float inv = 1.f / lt;
    // ---- transpose O^T[d][q] -> O[q][d] via per-wave padded LDS ----
    u16* tw = &tlds[wv][0];
    u32* tw32 = (u32*)tw;
#pragma unroll
    for (int i = 0; i < 8; ++i) {
        const int dl = 2 * (i & 1) + 8 * (i >> 1) + 4 * hi;  // crow(2i,hi)
        tw32[(l31 * 68 + dl) >> 1]      = cvtpk(ot0[2 * i] * inv, ot0[2 * i + 1] * inv);
        tw32[(l31 * 68 + dl + 32) >> 1] = cvtpk(ot1[2 * i] * inv, ot1[2 * i + 1] * inv);
    }
    __syncthreads();
    const int b = bh / 12, h = bh - b * 12;
    const size_t obase = ((size_t)(b << 10) + q0) * 768 + h * 64 + (lane & 7) * 8;
#pragma unroll
    for (int it = 0; it < 4; ++it) {
        const int r = it * 8 + (lane >> 3);
        bf16x8 v = *(const bf16x8*)&tw[r * 68 + (lane & 7) * 8];
        *(bf16x8*)&O[obase + (size_t)r * 768] = v;
    }
}

extern "C" void kernel_launch(void* const* d_in, const int* in_sizes, int n_in,
                              void* d_out, int out_size, void* d_ws, size_t ws_size,
                              hipStream_t stream) {
    const float* x      = (const float*)d_in[0];   // [8,1024,768]
    const float* w_qkv  = (const float*)d_in[1];   // [2304,768]
    const float* q_bias = (const float*)d_in[2];   // [768]
    const float* v_bias = (const float*)d_in[3];   // [768]
    const float* w_proj = (const float*)d_in[4];   // [768,768]
    const float* b_proj = (const float*)d_in[5];   // [768]
    float* out = (float*)d_out;                    // [8,1024,768] fp32

    char* ws = (char*)d_ws;
    u16* xb     = (u16*)(ws);                       // 12,582,912 B
    u16* wqkvb  = (u16*)(ws + 12582912);            //  3,538,944 B
    u16* wprojb = (u16*)(ws + 16121856);            //  1,179,648 B
    u16* qw     = (u16*)(ws + 17301504);            // 12,582,912 B
    u16* kw     = (u16*)(ws + 29884416);            // 12,582,912 B  (K fragment-order)
    u16* vt     = (u16*)(ws + 42467328);            // 12,582,912 B  (V fragment-order)
    u16* ob     = (u16*)(ws + 55050240);            // 12,582,912 B  (end 67.6 MB)

    cvt_kernel<<<786432 / 256, 256, 0, stream>>>(x, xb, 786432);
    cvt_kernel<<<221184 / 256, 256, 0, stream>>>(w_qkv, wqkvb, 221184);
    cvt_kernel<<< 73728 / 256, 256, 0, stream>>>(w_proj, wprojb, 73728);

    gemm_bt<0><<<(8192 / 128) * (2304 / 128), 256, 0, stream>>>(
        xb, wqkvb, 8192, 2304, 768, qw, kw, vt, q_bias, v_bias, nullptr, nullptr);

    attn_fwd<<<96 * 8, 256, 0, stream>>>(qw, kw, vt, ob);

    gemm_bt<1><<<(8192 / 128) * (768 / 128), 256, 0, stream>>>(
        ob, wprojb, 8192, 768, 768, nullptr, nullptr, nullptr, nullptr, nullptr, out, b_proj);
}

// Round 5
// 123.295 us; speedup vs baseline: 1.8156x; 1.0486x over previous
//
#include <hip/hip_runtime.h>
#include <hip/hip_bf16.h>

typedef unsigned short u16;
typedef unsigned int u32;
typedef __attribute__((ext_vector_type(4))) float f32x4;
typedef __attribute__((ext_vector_type(16))) float f32x16;
typedef __attribute__((ext_vector_type(8))) short bf16x8;

__device__ inline u16 f2bf(float f) {
    union { float f; u32 u; } v; v.f = f;
    u32 r = v.u + 0x7fff + ((v.u >> 16) & 1);
    return (u16)(r >> 16);
}

__device__ inline f32x4 mfma16(bf16x8 a, bf16x8 b, f32x4 c) {
    return __builtin_amdgcn_mfma_f32_16x16x32_bf16(a, b, c, 0, 0, 0);
}
__device__ inline f32x16 mfma32(bf16x8 a, bf16x8 b, f32x16 c) {
    return __builtin_amdgcn_mfma_f32_32x32x16_bf16(a, b, c, 0, 0, 0);
}
__device__ inline u32 cvtpk(float lo, float hi) {
    u32 r;
    asm("v_cvt_pk_bf16_f32 %0, %1, %2" : "=v"(r) : "v"(lo), "v"(hi));
    return r;
}
__device__ inline float exp2v(float x) {   // v_exp_f32: D = 2^S0 (TRANS pipe)
    float r;
    asm("v_exp_f32 %0, %1" : "=v"(r) : "v"(x));
    return r;
}

__device__ inline void gload_lds16(const void* g, const void* l) {
    __builtin_amdgcn_global_load_lds(
        (const __attribute__((address_space(1))) void*)g,
        (__attribute__((address_space(3))) void*)l, 16, 0, 0);
}

// log2(e) * head_dim^-0.5 — folded into q in the QKV epilogue (base-2 softmax)
#define QSCALE 0.18033688f

// ---------------- fp32 -> bf16 conversion, 8 elems/thread ----------------
__global__ void cvt_kernel(const float* __restrict__ in, u16* __restrict__ out, int n8) {
    int i = blockIdx.x * 256 + threadIdx.x;
    if (i >= n8) return;
    const float4* p = (const float4*)in;
    float4 a = p[2 * i], b = p[2 * i + 1];
    bf16x8 v;
    v[0] = (short)f2bf(a.x); v[1] = (short)f2bf(a.y);
    v[2] = (short)f2bf(a.z); v[3] = (short)f2bf(a.w);
    v[4] = (short)f2bf(b.x); v[5] = (short)f2bf(b.y);
    v[6] = (short)f2bf(b.z); v[7] = (short)f2bf(b.w);
    ((bf16x8*)out)[i] = v;
}

// ---------------- GEMM  C[M,N] = A[M,K] * B[N,K]^T  (bf16 in, f32 acc) ---
// 128x128 tile, 4 waves (2x2 of 64x64), BK=32, 2-phase gload_lds dbuf.
// XCD-aware block swizzle (grid % 8 == 0).
// EPI 0 (N=2304): tile is entirely Q, K, or V (part = col0/768).
//   Epilogue stages the 128x128 bf16 tile in LDS (reusing the 32KB
//   double-buffer), then writes fully-coalesced 16B chunks:
//   Q row-major [bh][n][64]*QSCALE
//   Kf: elem(n,d) -> (bh<<16) + (n>>5)*2048 + (d>>3)*256 + (n&31)*8 + (d&7)
//   Vf: elem(n,d) -> (bh<<16) + (n>>5)*2048 + ((d>>5)*2+((n&31)>>4))*512
//                    + (((n>>3)&1)*32 + (d&31))*8 + (n&7)
// EPI 1: fp32 out [M][N] + bias
template <int EPI>
__global__ __launch_bounds__(256) void gemm_bt(
    const u16* __restrict__ A, const u16* __restrict__ B,
    int M, int N, int K,
    u16* __restrict__ qw, u16* __restrict__ kw, u16* __restrict__ vw,
    const float* __restrict__ qb, const float* __restrict__ vb,
    float* __restrict__ outp, const float* __restrict__ bproj)
{
    __shared__ __align__(16) u16 smem[16384];   // 32 KB: lA[2] | lB[2], reused as C-tile
    u16* lA0 = smem;
    u16* lA1 = smem + 4096;
    u16* lB0 = smem + 8192;
    u16* lB1 = smem + 12288;

    const int tid = threadIdx.x;
    const int lane = tid & 63;
    const int wv = tid >> 6;
    const int nbn = N >> 7;
    // bijective XCD swizzle: XCD x executes a contiguous chunk of tiles
    const int nwg = gridDim.x;
    const int wg = (blockIdx.x & 7) * (nwg >> 3) + (blockIdx.x >> 3);
    const int bm = wg / nbn, bn = wg % nbn;
    const int row0 = bm << 7, col0 = bn << 7;

    const int c0 = tid, c1 = tid + 256;                 // 16B chunk ids
    const int ldsOff0 = (wv * 64) * 8;                  // ushort offset, wave-uniform
    const int ldsOff1 = (256 + wv * 64) * 8;

    f32x4 acc[4][4];
#pragma unroll
    for (int i = 0; i < 4; i++)
#pragma unroll
        for (int j = 0; j < 4; j++) acc[i][j] = (f32x4){0.f, 0.f, 0.f, 0.f};

    const int nT = K >> 5;

    auto stage = [&](u16* bufA, u16* bufB, int t) {
        const int k0 = t << 5;
        gload_lds16(&A[(size_t)(row0 + (c0 >> 2)) * K + k0 + (c0 & 3) * 8], bufA + ldsOff0);
        gload_lds16(&A[(size_t)(row0 + (c1 >> 2)) * K + k0 + (c1 & 3) * 8], bufA + ldsOff1);
        gload_lds16(&B[(size_t)(col0 + (c0 >> 2)) * K + k0 + (c0 & 3) * 8], bufB + ldsOff0);
        gload_lds16(&B[(size_t)(col0 + (c1 >> 2)) * K + k0 + (c1 & 3) * 8], bufB + ldsOff1);
    };

    const int wr = (wv >> 1) << 6;   // wave row offset 0/64
    const int wc = (wv & 1) << 6;    // wave col offset 0/64

    stage(lA0, lB0, 0);
    __syncthreads();
    for (int t = 0; t < nT; ++t) {
        const u16* As = ((t & 1) ? lA1 : lA0) + (wr + (lane & 15)) * 32 + ((lane >> 4) * 8);
        const u16* Bs = ((t & 1) ? lB1 : lB0) + (wc + (lane & 15)) * 32 + ((lane >> 4) * 8);
        if (t + 1 < nT)
            stage((t & 1) ? lA0 : lA1, (t & 1) ? lB0 : lB1, t + 1);
        bf16x8 af[4], bfr[4];
#pragma unroll
        for (int i = 0; i < 4; i++) af[i] = *(const bf16x8*)(As + i * 16 * 32);
#pragma unroll
        for (int i = 0; i < 4; i++) bfr[i] = *(const bf16x8*)(Bs + i * 16 * 32);
#pragma unroll
        for (int i = 0; i < 4; i++)
#pragma unroll
            for (int j = 0; j < 4; j++)
                acc[i][j] = mfma16(af[i], bfr[j], acc[i][j]);
        __syncthreads();
    }
    // (loop ends with a barrier: smem is free for reuse)

    if (EPI == 0) {
        const int part = col0 / 768;          // block-uniform: 0=Q 1=K 2=V
        const int colr0 = col0 - part * 768;  // multiple of 128
        const int h0 = colr0 >> 6;            // first of 2 heads in tile
        const int bb = row0 >> 10;            // batch
        const int n0 = row0 & 1023;           // multiple of 128

        // ---- stage tile into LDS (16B-chunk XOR swizzle vs row) ----
        if (part < 2) {
            // row-major [row][col]
#pragma unroll
            for (int nj = 0; nj < 4; ++nj) {
                const int col = wc + nj * 16 + (lane & 15);
                const float bias = (part == 0) ? qb[colr0 + col] : 0.f;
                const float sc = (part == 0) ? QSCALE : 1.f;
#pragma unroll
                for (int mi = 0; mi < 4; ++mi) {
#pragma unroll
                    for (int j = 0; j < 4; ++j) {
                        const int row = wr + mi * 16 + ((lane >> 4) << 2) + j;
                        smem[row * 128 + ((((col >> 3) ^ (row & 7)) << 3) | (col & 7))] =
                            f2bf((acc[mi][nj][j] + bias) * sc);
                    }
                }
            }
        } else {
            // transposed [col][row], 4 consecutive rows pack to one b64
#pragma unroll
            for (int nj = 0; nj < 4; ++nj) {
                const int col = wc + nj * 16 + (lane & 15);
                const float bias = vb[colr0 + col];
#pragma unroll
                for (int mi = 0; mi < 4; ++mi) {
                    const int row = wr + mi * 16 + ((lane >> 4) << 2);  // row..row+3
                    ushort4 pk;
                    pk.x = f2bf(acc[mi][nj][0] + bias);
                    pk.y = f2bf(acc[mi][nj][1] + bias);
                    pk.z = f2bf(acc[mi][nj][2] + bias);
                    pk.w = f2bf(acc[mi][nj][3] + bias);
                    *(ushort4*)&smem[col * 128 +
                        ((((row >> 3) ^ (col & 7)) << 3) | (row & 7))] = pk;
                }
            }
        }
        __syncthreads();

        // ---- coalesced write-out: 8 passes x 256 threads x 16B ----
        if (part == 0) {
#pragma unroll
            for (int p = 0; p < 8; ++p) {
                const int c = p * 256 + tid;
                const int h = c >> 10, ri = (c >> 3) & 127, j = c & 7;
                bf16x8 v = *(const bf16x8*)&smem[ri * 128 + (((h * 8 + j) ^ (ri & 7)) << 3)];
                *(bf16x8*)&qw[((size_t)(((bb * 12 + h0 + h) << 10) + n0 + ri)) * 64 + j * 8] = v;
            }
        } else if (part == 1) {
#pragma unroll
            for (int p = 0; p < 8; ++p) {
                const int c = p * 256 + tid;
                const int h = c >> 10, t2 = (c >> 8) & 3, j = (c >> 5) & 7, r = c & 31;
                const int ri = t2 * 32 + r;
                bf16x8 v = *(const bf16x8*)&smem[ri * 128 + (((h * 8 + j) ^ (ri & 7)) << 3)];
                *(bf16x8*)&kw[((size_t)(bb * 12 + h0 + h) << 16) +
                              (((n0 >> 5) + t2) << 11) + (j << 8) + (r << 3)] = v;
            }
        } else {
#pragma unroll
            for (int p = 0; p < 8; ++p) {
                const int c = p * 256 + tid;
                const int h = c >> 10, w = c & 1023;
                const int t2 = w >> 8, f = (w >> 6) & 3, ln = w & 63;
                const int d = ((f >> 1) << 5) + (ln & 31);
                const int rb = t2 * 32 + ((f & 1) << 4) + ((ln >> 5) << 3);
                const int ct = h * 64 + d;
                bf16x8 v = *(const bf16x8*)&smem[ct * 128 + (((rb >> 3) ^ (ct & 7)) << 3)];
                *(bf16x8*)&vw[((size_t)(bb * 12 + h0 + h) << 16) +
                              (((n0 >> 5) + t2) << 11) + (f << 9) + (ln << 3)] = v;
            }
        }
    } else {
#pragma unroll
        for (int nj = 0; nj < 4; ++nj) {
            const int col = col0 + wc + nj * 16 + (lane & 15);
            const float bias = bproj[col];
#pragma unroll
            for (int mi = 0; mi < 4; ++mi) {
#pragma unroll
                for (int j = 0; j < 4; ++j) {
                    const int row = row0 + wr + mi * 16 + ((lane >> 4) << 2) + j;
                    outp[(size_t)row * N + col] = acc[mi][nj][j] + bias;
                }
            }
        }
    }
}

// ---------------- flash attention, swapped-operand 32x32 MFMA ------------
// 1 wave = 32 q-rows, 4 waves/block, no barriers in kv loop.
// K and V read from FRAGMENT-ORDER global layouts: every load instruction
// is a contiguous 1KB (8 fully-used cache lines). K(t+1) prefetched into a
// second register set (2x manual unroll).
__global__ __launch_bounds__(256, 3) void attn_fwd(
    const u16* __restrict__ Q, const u16* __restrict__ KF,
    const u16* __restrict__ VF, u16* __restrict__ O)
{
    __shared__ __align__(16) u16 tlds[4][32 * 68];   // output transpose, pad 68
    const int tid = threadIdx.x, lane = tid & 63, wv = tid >> 6;
    const int l31 = lane & 31, hi = lane >> 5;
    const int bh = blockIdx.x % 96;    // 96%8==0: one head -> one XCD
    const int qbk = blockIdx.x / 96;
    const int q0 = qbk * 128 + wv * 32;
    const size_t base = (size_t)bh << 16;
    const u16* Qp = Q + base;
    const u16* Kp = KF + base;
    const u16* Vp = VF + base;

    bf16x8 qf0, qf1, qf2, qf3;
    {
        const u16* qrow = &Qp[(q0 + l31) * 64 + hi * 8];
        qf0 = *(const bf16x8*)(qrow);
        qf1 = *(const bf16x8*)(qrow + 16);
        qf2 = *(const bf16x8*)(qrow + 32);
        qf3 = *(const bf16x8*)(qrow + 48);
    }

    f32x16 ot0, ot1;
#pragma unroll
    for (int i = 0; i < 16; ++i) { ot0[i] = 0.f; ot1[i] = 0.f; }
    float m = -1e30f, l = 0.f;

    // Kf tile t: chunk j=2i+hi at t*2048 + (2i+hi)*256 + l31*8
    auto loadK = [&](int t2048, bf16x8& f0, bf16x8& f1, bf16x8& f2, bf16x8& f3) {
        const u16* kr = &Kp[t2048 + hi * 256 + l31 * 8];
        f0 = *(const bf16x8*)(kr);
        f1 = *(const bf16x8*)(kr + 512);
        f2 = *(const bf16x8*)(kr + 1024);
        f3 = *(const bf16x8*)(kr + 1536);
    };

    auto body = [&](int t2048, bf16x8 k0, bf16x8 k1, bf16x8 k2, bf16x8 k3) {
        f32x16 s;
#pragma unroll
        for (int i = 0; i < 16; ++i) s[i] = 0.f;
        __builtin_amdgcn_s_setprio(1);
        s = mfma32(k0, qf0, s);
        s = mfma32(k1, qf1, s);
        s = mfma32(k2, qf2, s);
        s = mfma32(k3, qf3, s);
        __builtin_amdgcn_s_setprio(0);
        // V fragments: contiguous 1KB each, issued before softmax
        const u16* vrow = &Vp[t2048 + lane * 8];
        bf16x8 vf00 = *(const bf16x8*)(vrow);           // f=0: d 0-31,  k 0-15
        bf16x8 vf01 = *(const bf16x8*)(vrow + 512);     // f=1: d 0-31,  k 16-31
        bf16x8 vf10 = *(const bf16x8*)(vrow + 1024);    // f=2: d 32-63, k 0-15
        bf16x8 vf11 = *(const bf16x8*)(vrow + 1536);    // f=3: d 32-63, k 16-31
        // ---- online softmax (base-2), fully in-register ----
        float t0 = fmaxf(fmaxf(s[0], s[1]), fmaxf(s[2], s[3]));
        float t1 = fmaxf(fmaxf(s[4], s[5]), fmaxf(s[6], s[7]));
        float t2 = fmaxf(fmaxf(s[8], s[9]), fmaxf(s[10], s[11]));
        float t3 = fmaxf(fmaxf(s[12], s[13]), fmaxf(s[14], s[15]));
        float tmax = fmaxf(fmaxf(t0, t1), fmaxf(t2, t3));
        tmax = fmaxf(tmax, __shfl_xor(tmax, 32));
        if (!__all(tmax - m <= 8.f)) {   // defer-max (T13), 2^8 headroom
            const float nm = fmaxf(m, tmax);
            const float cr = exp2v(m - nm);
#pragma unroll
            for (int i = 0; i < 16; ++i) { ot0[i] *= cr; ot1[i] *= cr; }
            l *= cr; m = nm;
        }
#pragma unroll
        for (int i = 0; i < 16; ++i) { float p = exp2v(s[i] - m); s[i] = p; l += p; }
        // ---- P -> bf16 PV B-frags via cvt_pk + permlane32_swap (T12) ----
        u32 w0 = cvtpk(s[0],  s[1]),  w1 = cvtpk(s[2],  s[3]);
        u32 w2 = cvtpk(s[4],  s[5]),  w3 = cvtpk(s[6],  s[7]);
        u32 w4 = cvtpk(s[8],  s[9]),  w5 = cvtpk(s[10], s[11]);
        u32 w6 = cvtpk(s[12], s[13]), w7 = cvtpk(s[14], s[15]);
        asm("v_permlane32_swap_b32 %0, %1" : "+v"(w0), "+v"(w2));
        asm("v_permlane32_swap_b32 %0, %1" : "+v"(w1), "+v"(w3));
        asm("v_permlane32_swap_b32 %0, %1" : "+v"(w4), "+v"(w6));
        asm("v_permlane32_swap_b32 %0, %1" : "+v"(w5), "+v"(w7));
        union { u32 u[4]; bf16x8 v; } pb0, pb1;
        pb0.u[0] = w0; pb0.u[1] = w1; pb0.u[2] = w2; pb0.u[3] = w3;
        pb1.u[0] = w4; pb1.u[1] = w5; pb1.u[2] = w6; pb1.u[3] = w7;
        __builtin_amdgcn_s_setprio(1);
        ot0 = mfma32(vf00, pb0.v, ot0);
        ot0 = mfma32(vf01, pb1.v, ot0);
        ot1 = mfma32(vf10, pb0.v, ot1);
        ot1 = mfma32(vf11, pb1.v, ot1);
        __builtin_amdgcn_s_setprio(0);
    };

    bf16x8 ka0, ka1, ka2, ka3, kb0, kb1, kb2, kb3;
    loadK(0, ka0, ka1, ka2, ka3);
    for (int kt = 0; kt < 32; kt += 2) {
        loadK((kt + 1) << 11, kb0, kb1, kb2, kb3);   // prefetch t+1
        body(kt << 11, ka0, ka1, ka2, ka3);
        if (kt + 2 < 32) loadK((kt + 2) << 11, ka0, ka1, ka2, ka3);  // prefetch t+2
        body((kt + 1) << 11, kb0, kb1, kb2, kb3);
    }

    const float lt = l + __shfl_xor(l, 32);
    const float inv = 1.f / lt;
    // ---- transpose O^T[d][q] -> O[q][d] via per-wave padded LDS ----
    u16* tw = &tlds[wv][0];
    u32* tw32 = (u32*)tw;
#pragma unroll
    for (int i = 0; i < 8; ++i) {
        const int dl = 2 * (i & 1) + 8 * (i >> 1) + 4 * hi;  // crow(2i,hi)
        tw32[(l31 * 68 + dl) >> 1]      = cvtpk(ot0[2 * i] * inv, ot0[2 * i + 1] * inv);
        tw32[(l31 * 68 + dl + 32) >> 1] = cvtpk(ot1[2 * i] * inv, ot1[2 * i + 1] * inv);
    }
    __syncthreads();
    const int b = bh / 12, h = bh - b * 12;
    const size_t obase = ((size_t)(b << 10) + q0) * 768 + h * 64 + (lane & 7) * 8;
#pragma unroll
    for (int it = 0; it < 4; ++it) {
        const int r = it * 8 + (lane >> 3);
        bf16x8 v = *(const bf16x8*)&tw[r * 68 + (lane & 7) * 8];
        *(bf16x8*)&O[obase + (size_t)r * 768] = v;
    }
}

extern "C" void kernel_launch(void* const* d_in, const int* in_sizes, int n_in,
                              void* d_out, int out_size, void* d_ws, size_t ws_size,
                              hipStream_t stream) {
    const float* x      = (const float*)d_in[0];   // [8,1024,768]
    const float* w_qkv  = (const float*)d_in[1];   // [2304,768]
    const float* q_bias = (const float*)d_in[2];   // [768]
    const float* v_bias = (const float*)d_in[3];   // [768]
    const float* w_proj = (const float*)d_in[4];   // [768,768]
    const float* b_proj = (const float*)d_in[5];   // [768]
    float* out = (float*)d_out;                    // [8,1024,768] fp32

    char* ws = (char*)d_ws;
    u16* xb     = (u16*)(ws);                       // 12,582,912 B
    u16* wqkvb  = (u16*)(ws + 12582912);            //  3,538,944 B
    u16* wprojb = (u16*)(ws + 16121856);            //  1,179,648 B
    u16* qw     = (u16*)(ws + 17301504);            // 12,582,912 B
    u16* kw     = (u16*)(ws + 29884416);            // 12,582,912 B  (K fragment-order)
    u16* vt     = (u16*)(ws + 42467328);            // 12,582,912 B  (V fragment-order)
    u16* ob     = (u16*)(ws + 55050240);            // 12,582,912 B  (end 67.6 MB)

    cvt_kernel<<<786432 / 256, 256, 0, stream>>>(x, xb, 786432);
    cvt_kernel<<<221184 / 256, 256, 0, stream>>>(w_qkv, wqkvb, 221184);
    cvt_kernel<<< 73728 / 256, 256, 0, stream>>>(w_proj, wprojb, 73728);

    gemm_bt<0><<<(8192 / 128) * (2304 / 128), 256, 0, stream>>>(
        xb, wqkvb, 8192, 2304, 768, qw, kw, vt, q_bias, v_bias, nullptr, nullptr);

    attn_fwd<<<96 * 8, 256, 0, stream>>>(qw, kw, vt, ob);

    gemm_bt<1><<<(8192 / 128) * (768 / 128), 256, 0, stream>>>(
        ob, wprojb, 8192, 768, 768, nullptr, nullptr, nullptr, nullptr, nullptr, out, b_proj);
}